// Round 1
// baseline (11998.621 us; speedup 1.0000x reference)
//
#include <hip/hip_runtime.h>

// Problem constants
#define B_   4
#define T_   1024
#define C_   1024
#define H_   16
#define HD_  64
#define L_   6
#define V_   16000
#define FF_  4096
#define TTXT_ 580
#define NPATCH_ 441

// ---------------------------------------------------------------------------
// Tiled fp32 GEMM: C[M,N] = A[M,K] @ B[K,N] (+bias) (+res) (relu)
// BM=128, BN=64, BK=32; 256 threads; 8x4 microtile per thread.
// M % 128 == 0, N % 64 == 0, K % 32 == 0 for all our shapes.
// ---------------------------------------------------------------------------
template<bool BIAS, bool RES, bool RELU>
__global__ __launch_bounds__(256, 2)
void gemm_kernel(const float* __restrict__ A, const float* __restrict__ Bm,
                 const float* __restrict__ bias, const float* __restrict__ res,
                 float* __restrict__ C, int M, int N, int K)
{
    constexpr int BM = 128, BN = 64, BK = 32;
    __shared__ float As[BK][BM + 4];   // stride 132: b128 reads aligned, conflict-free
    __shared__ float Bs[BK][BN];

    const int tid = threadIdx.x;
    const int tx = tid & 15;           // N dir: cols tx*4 .. tx*4+3
    const int ty = tid >> 4;           // M dir: rows ty*8 .. ty*8+7
    const int m0 = blockIdx.y * BM, n0 = blockIdx.x * BN;

    float acc[8][4];
#pragma unroll
    for (int r = 0; r < 8; ++r)
#pragma unroll
        for (int c = 0; c < 4; ++c) acc[r][c] = 0.f;

    const int nkt = K / BK;
    for (int kt = 0; kt < nkt; ++kt) {
        // A tile: 128x32, transposed store -> As[k][m]
#pragma unroll
        for (int it = 0; it < 4; ++it) {
            int f = tid + it * 256;          // 0..1023
            int row = f >> 3, colv = f & 7;  // 8 float4 per 32-col row
            float4 av = *reinterpret_cast<const float4*>(
                &A[(size_t)(m0 + row) * K + (size_t)kt * BK + colv * 4]);
            As[colv * 4 + 0][row] = av.x;
            As[colv * 4 + 1][row] = av.y;
            As[colv * 4 + 2][row] = av.z;
            As[colv * 4 + 3][row] = av.w;
        }
        // B tile: 32x64, natural store
#pragma unroll
        for (int it = 0; it < 2; ++it) {
            int f = tid + it * 256;           // 0..511
            int krow = f >> 4, colv = f & 15; // 16 float4 per 64-col row
            float4 bv = *reinterpret_cast<const float4*>(
                &Bm[(size_t)(kt * BK + krow) * N + n0 + colv * 4]);
            *reinterpret_cast<float4*>(&Bs[krow][colv * 4]) = bv;
        }
        __syncthreads();

#pragma unroll
        for (int kk = 0; kk < BK; ++kk) {
            float4 b4 = *reinterpret_cast<const float4*>(&Bs[kk][tx * 4]);
            float4 a0 = *reinterpret_cast<const float4*>(&As[kk][ty * 8]);
            float4 a1 = *reinterpret_cast<const float4*>(&As[kk][ty * 8 + 4]);
            float a[8] = {a0.x, a0.y, a0.z, a0.w, a1.x, a1.y, a1.z, a1.w};
            float bb[4] = {b4.x, b4.y, b4.z, b4.w};
#pragma unroll
            for (int r = 0; r < 8; ++r)
#pragma unroll
                for (int c = 0; c < 4; ++c)
                    acc[r][c] = fmaf(a[r], bb[c], acc[r][c]);
        }
        __syncthreads();
    }

    float4 bias4 = {0.f, 0.f, 0.f, 0.f};
    if (BIAS) bias4 = *reinterpret_cast<const float4*>(&bias[n0 + tx * 4]);

#pragma unroll
    for (int r = 0; r < 8; ++r) {
        int row = m0 + ty * 8 + r;
        size_t off = (size_t)row * N + n0 + tx * 4;
        float4 v;
        v.x = acc[r][0]; v.y = acc[r][1]; v.z = acc[r][2]; v.w = acc[r][3];
        if (BIAS) { v.x += bias4.x; v.y += bias4.y; v.z += bias4.z; v.w += bias4.w; }
        if (RES) {
            float4 rv = *reinterpret_cast<const float4*>(&res[off]);
            v.x += rv.x; v.y += rv.y; v.z += rv.z; v.w += rv.w;
        }
        if (RELU) {
            v.x = fmaxf(v.x, 0.f); v.y = fmaxf(v.y, 0.f);
            v.z = fmaxf(v.z, 0.f); v.w = fmaxf(v.w, 0.f);
        }
        *reinterpret_cast<float4*>(&C[off]) = v;
    }
}

// ---------------------------------------------------------------------------
// LayerNorm: one block per row (C=1024), 256 threads, float4 per thread.
// ---------------------------------------------------------------------------
__global__ __launch_bounds__(256)
void ln_kernel(const float* __restrict__ x, const float* __restrict__ g,
               const float* __restrict__ bta, float* __restrict__ out)
{
    const int row = blockIdx.x;
    const int tid = threadIdx.x;
    const float4* xr = reinterpret_cast<const float4*>(x + (size_t)row * C_);
    float4 xv = xr[tid];
    float s = xv.x + xv.y + xv.z + xv.w;
    float ss = xv.x * xv.x + xv.y * xv.y + xv.z * xv.z + xv.w * xv.w;
#pragma unroll
    for (int off = 1; off < 64; off <<= 1) {
        s  += __shfl_xor(s, off);
        ss += __shfl_xor(ss, off);
    }
    __shared__ float red[8];
    int wave = tid >> 6, lane = tid & 63;
    if (lane == 0) { red[wave * 2] = s; red[wave * 2 + 1] = ss; }
    __syncthreads();
    s  = red[0] + red[2] + red[4] + red[6];
    ss = red[1] + red[3] + red[5] + red[7];
    float mean = s * (1.f / C_);
    float var = ss * (1.f / C_) - mean * mean;
    float rs = rsqrtf(var + 1e-5f);
    float4 gv = reinterpret_cast<const float4*>(g)[tid];
    float4 bv = reinterpret_cast<const float4*>(bta)[tid];
    float4 ov;
    ov.x = (xv.x - mean) * rs * gv.x + bv.x;
    ov.y = (xv.y - mean) * rs * gv.y + bv.y;
    ov.z = (xv.z - mean) * rs * gv.z + bv.z;
    ov.w = (xv.w - mean) * rs * gv.w + bv.w;
    reinterpret_cast<float4*>(out + (size_t)row * C_)[tid] = ov;
}

// ---------------------------------------------------------------------------
// Flash attention fp32. Grid: (T/64, B*H). 256 threads.
// Q tile 64x64 staged transposed; per kv-tile: S=QK^T, online softmax, P@V.
// KPs buffer is K (transposed) then reused for P (natural [i][j]).
// ---------------------------------------------------------------------------
__global__ __launch_bounds__(256, 2)
void attn_kernel(const float* __restrict__ q, const float* __restrict__ k,
                 const float* __restrict__ v, float* __restrict__ o)
{
    __shared__ float Qs[64][68];   // [d][i]
    __shared__ float KPs[64][68];  // K: [d][j] ; P: [i][j]
    __shared__ float Vs[64][64];   // [j][d]

    const int tid = threadIdx.x;
    const int tx = tid & 15;       // cols (j or d): tx*4..+3
    const int ty = tid >> 4;       // q rows: ty*4..+3
    const int qt = blockIdx.x;
    const int bh = blockIdx.y;
    const int b = bh >> 4, h = bh & 15;

    const size_t base = (size_t)b * T_ * C_ + (size_t)h * HD_;
    const float* qb = q + base;
    const float* kb = k + base;
    const float* vb = v + base;
    float* ob = o + base;

    // load Q tile transposed: Qs[d][i]
#pragma unroll
    for (int it = 0; it < 4; ++it) {
        int f = tid + it * 256;          // 0..1023
        int row = f >> 4, colv = f & 15;
        float4 qv = *reinterpret_cast<const float4*>(
            &qb[(size_t)(qt * 64 + row) * C_ + colv * 4]);
        Qs[colv * 4 + 0][row] = qv.x;
        Qs[colv * 4 + 1][row] = qv.y;
        Qs[colv * 4 + 2][row] = qv.z;
        Qs[colv * 4 + 3][row] = qv.w;
    }

    float o_acc[4][4];
    float m[4], l[4];
#pragma unroll
    for (int r = 0; r < 4; ++r) {
        m[r] = -1e30f; l[r] = 0.f;
#pragma unroll
        for (int c = 0; c < 4; ++c) o_acc[r][c] = 0.f;
    }

    for (int kt = 0; kt <= qt; ++kt) {
        __syncthreads();  // prior tile's P@V done with KPs/Vs
        // K tile transposed; V tile natural
#pragma unroll
        for (int it = 0; it < 4; ++it) {
            int f = tid + it * 256;
            int row = f >> 4, colv = f & 15;
            float4 kv = *reinterpret_cast<const float4*>(
                &kb[(size_t)(kt * 64 + row) * C_ + colv * 4]);
            KPs[colv * 4 + 0][row] = kv.x;
            KPs[colv * 4 + 1][row] = kv.y;
            KPs[colv * 4 + 2][row] = kv.z;
            KPs[colv * 4 + 3][row] = kv.w;
            float4 vv = *reinterpret_cast<const float4*>(
                &vb[(size_t)(kt * 64 + row) * C_ + colv * 4]);
            *reinterpret_cast<float4*>(&Vs[row][colv * 4]) = vv;
        }
        __syncthreads();

        // S = Q @ K^T
        float s[4][4];
#pragma unroll
        for (int r = 0; r < 4; ++r)
#pragma unroll
            for (int c = 0; c < 4; ++c) s[r][c] = 0.f;
        for (int d = 0; d < 64; ++d) {
            float4 a4 = *reinterpret_cast<const float4*>(&Qs[d][ty * 4]);
            float4 b4 = *reinterpret_cast<const float4*>(&KPs[d][tx * 4]);
            float a[4] = {a4.x, a4.y, a4.z, a4.w};
            float bb[4] = {b4.x, b4.y, b4.z, b4.w};
#pragma unroll
            for (int r = 0; r < 4; ++r)
#pragma unroll
                for (int c = 0; c < 4; ++c)
                    s[r][c] = fmaf(a[r], bb[c], s[r][c]);
        }

        const bool diag = (kt == qt);
#pragma unroll
        for (int r = 0; r < 4; ++r) {
            int qi = qt * 64 + ty * 4 + r;
#pragma unroll
            for (int c = 0; c < 4; ++c) {
                s[r][c] *= 0.125f;  // HD^-0.5
                if (diag) {
                    int kj = kt * 64 + tx * 4 + c;
                    if (kj > qi) s[r][c] = -1e30f;
                }
            }
            // row max over this thread's 4, then across the 16 tx lanes
            float tmax = fmaxf(fmaxf(s[r][0], s[r][1]), fmaxf(s[r][2], s[r][3]));
#pragma unroll
            for (int off = 1; off < 16; off <<= 1)
                tmax = fmaxf(tmax, __shfl_xor(tmax, off));
            float mnew = fmaxf(m[r], tmax);
            float corr = __expf(m[r] - mnew);
            float psum = 0.f;
#pragma unroll
            for (int c = 0; c < 4; ++c) {
                s[r][c] = __expf(s[r][c] - mnew);
                psum += s[r][c];
            }
#pragma unroll
            for (int off = 1; off < 16; off <<= 1)
                psum += __shfl_xor(psum, off);
            l[r] = l[r] * corr + psum;
            m[r] = mnew;
#pragma unroll
            for (int c = 0; c < 4; ++c) o_acc[r][c] *= corr;
        }

        __syncthreads();  // everyone done reading KPs as K
        // write P into KPs as [i][j]
#pragma unroll
        for (int r = 0; r < 4; ++r) {
            float4 pv;
            pv.x = s[r][0]; pv.y = s[r][1]; pv.z = s[r][2]; pv.w = s[r][3];
            *reinterpret_cast<float4*>(&KPs[ty * 4 + r][tx * 4]) = pv;
        }
        __syncthreads();

        // O += P @ V
        for (int j = 0; j < 64; ++j) {
            float4 b4 = *reinterpret_cast<const float4*>(&Vs[j][tx * 4]);
#pragma unroll
            for (int r = 0; r < 4; ++r) {
                float a = KPs[ty * 4 + r][j];
                o_acc[r][0] = fmaf(a, b4.x, o_acc[r][0]);
                o_acc[r][1] = fmaf(a, b4.y, o_acc[r][1]);
                o_acc[r][2] = fmaf(a, b4.z, o_acc[r][2]);
                o_acc[r][3] = fmaf(a, b4.w, o_acc[r][3]);
            }
        }
    }

#pragma unroll
    for (int r = 0; r < 4; ++r) {
        float inv = 1.f / l[r];
        float4 ov;
        ov.x = o_acc[r][0] * inv; ov.y = o_acc[r][1] * inv;
        ov.z = o_acc[r][2] * inv; ov.w = o_acc[r][3] * inv;
        *reinterpret_cast<float4*>(
            &ob[(size_t)(qt * 64 + ty * 4 + r) * C_ + tx * 4]) = ov;
    }
}

// ---------------------------------------------------------------------------
// Patch embedding: block per patch (441), 1024 threads (= channels).
// x[b, 2+np, c] = conv + patch_b + img_pos + txt_pos
// ---------------------------------------------------------------------------
__global__ __launch_bounds__(1024)
void patch_kernel(const float* __restrict__ images, const float* __restrict__ pw,
                  const float* __restrict__ pb, const float* __restrict__ img_pos,
                  const float* __restrict__ txt_pos, float* __restrict__ x)
{
    const int np = blockIdx.x;
    const int py = np / 21, px = np % 21;
    const int tid = threadIdx.x;

    __shared__ float pix[4][768];
#pragma unroll
    for (int it = 0; it < 3; ++it) {
        int f = tid + it * 1024;            // 0..3071
        int b = f / 768, r = f % 768;
        int ci = r >> 8, rem = r & 255, ky = rem >> 4, kx = rem & 15;
        pix[b][r] = images[(((size_t)b * 3 + ci) * 336 + py * 16 + ky) * 336
                           + px * 16 + kx];
    }
    __syncthreads();

    const int c = tid;
    float acc[4] = {0.f, 0.f, 0.f, 0.f};
    const float4* w4 = reinterpret_cast<const float4*>(pw + (size_t)c * 768);
    const float4* p4[4] = {
        reinterpret_cast<const float4*>(pix[0]),
        reinterpret_cast<const float4*>(pix[1]),
        reinterpret_cast<const float4*>(pix[2]),
        reinterpret_cast<const float4*>(pix[3])};
    for (int k4 = 0; k4 < 192; ++k4) {
        float4 w = w4[k4];
#pragma unroll
        for (int b = 0; b < 4; ++b) {
            float4 a = p4[b][k4];
            acc[b] = fmaf(w.x, a.x, acc[b]);
            acc[b] = fmaf(w.y, a.y, acc[b]);
            acc[b] = fmaf(w.z, a.z, acc[b]);
            acc[b] = fmaf(w.w, a.w, acc[b]);
        }
    }
    const float addc = pb[c] + img_pos[(size_t)np * C_ + c]
                     + txt_pos[(size_t)(2 + np) * C_ + c];
#pragma unroll
    for (int b = 0; b < 4; ++b)
        x[((size_t)b * T_ + 2 + np) * C_ + c] = acc[b] + addc;
}

// ---------------------------------------------------------------------------
// Fill bos / img_start / img_end / text rows: grid (583, B), 256 threads.
// ---------------------------------------------------------------------------
__global__ __launch_bounds__(256)
void fill_kernel(const int* __restrict__ toks, const float* __restrict__ tok_emb,
                 const float* __restrict__ txt_pos, float* __restrict__ x)
{
    const int idx = blockIdx.x;
    const int b = blockIdx.y;
    const int tid = threadIdx.x;
    int t, tok;
    if (idx == 0)      { t = 0;   tok = 1; }   // BOS
    else if (idx == 1) { t = 1;   tok = 8; }   // IMG_START
    else if (idx == 2) { t = 443; tok = 9; }   // IMG_END
    else { t = 444 + (idx - 3); tok = toks[b * TTXT_ + (idx - 3)]; }

    float4 e = reinterpret_cast<const float4*>(tok_emb + (size_t)tok * C_)[tid];
    float4 p = reinterpret_cast<const float4*>(txt_pos + (size_t)t * C_)[tid];
    e.x += p.x; e.y += p.y; e.z += p.z; e.w += p.w;
    reinterpret_cast<float4*>(x + ((size_t)b * T_ + t) * C_)[tid] = e;
}

// ---------------------------------------------------------------------------
extern "C" void kernel_launch(void* const* d_in, const int* in_sizes, int n_in,
                              void* d_out, int out_size, void* d_ws, size_t ws_size,
                              hipStream_t stream)
{
    const int*   toks    = (const int*)  d_in[0];
    const float* images  = (const float*)d_in[1];
    const float* tok_emb = (const float*)d_in[2];
    const float* txt_pos = (const float*)d_in[3];
    const float* img_pos = (const float*)d_in[4];
    const float* patch_w = (const float*)d_in[5];
    const float* patch_b = (const float*)d_in[6];
    const float* ln1_g   = (const float*)d_in[7];
    const float* ln1_b   = (const float*)d_in[8];
    const float* wq      = (const float*)d_in[9];
    const float* wk      = (const float*)d_in[10];
    const float* wv      = (const float*)d_in[11];
    const float* wo      = (const float*)d_in[12];
    const float* bo      = (const float*)d_in[13];
    const float* ln2_g   = (const float*)d_in[14];
    const float* ln2_b   = (const float*)d_in[15];
    const float* w1      = (const float*)d_in[16];
    const float* b1      = (const float*)d_in[17];
    const float* w2      = (const float*)d_in[18];
    const float* b2      = (const float*)d_in[19];
    const float* lnf_g   = (const float*)d_in[20];
    const float* lnf_b   = (const float*)d_in[21];
    const float* lm_w    = (const float*)d_in[22];
    const float* lm_b    = (const float*)d_in[23];
    float* out = (float*)d_out;

    const size_t NTC = (size_t)B_ * T_ * C_;   // 4,194,304 floats
    float* x   = (float*)d_ws;
    float* h   = x  + NTC;
    float* qb  = h  + NTC;
    float* kb  = qb + NTC;
    float* vb  = kb + NTC;
    float* ffn = vb + NTC;                     // 4096 x 4096

    const int M = B_ * T_;                     // 4096

    patch_kernel<<<NPATCH_, 1024, 0, stream>>>(images, patch_w, patch_b,
                                               img_pos, txt_pos, x);
    fill_kernel<<<dim3(3 + TTXT_, B_), 256, 0, stream>>>(toks, tok_emb, txt_pos, x);

    for (int l = 0; l < L_; ++l) {
        const size_t wofs = (size_t)l * C_ * C_;
        ln_kernel<<<M, 256, 0, stream>>>(x, ln1_g + l * C_, ln1_b + l * C_, h);
        gemm_kernel<false, false, false><<<dim3(C_ / 64, M / 128), 256, 0, stream>>>(
            h, wq + wofs, nullptr, nullptr, qb, M, C_, C_);
        gemm_kernel<false, false, false><<<dim3(C_ / 64, M / 128), 256, 0, stream>>>(
            h, wk + wofs, nullptr, nullptr, kb, M, C_, C_);
        gemm_kernel<false, false, false><<<dim3(C_ / 64, M / 128), 256, 0, stream>>>(
            h, wv + wofs, nullptr, nullptr, vb, M, C_, C_);
        attn_kernel<<<dim3(T_ / 64, B_ * H_), 256, 0, stream>>>(qb, kb, vb, h);
        gemm_kernel<true, true, false><<<dim3(C_ / 64, M / 128), 256, 0, stream>>>(
            h, wo + wofs, bo + l * C_, x, x, M, C_, C_);
        ln_kernel<<<M, 256, 0, stream>>>(x, ln2_g + l * C_, ln2_b + l * C_, h);
        gemm_kernel<true, false, true><<<dim3(FF_ / 64, M / 128), 256, 0, stream>>>(
            h, w1 + (size_t)l * C_ * FF_, b1 + (size_t)l * FF_, nullptr, ffn,
            M, FF_, C_);
        gemm_kernel<true, true, false><<<dim3(C_ / 64, M / 128), 256, 0, stream>>>(
            ffn, w2 + (size_t)l * FF_ * C_, b2 + l * C_, x, x, M, C_, FF_);
    }
    ln_kernel<<<M, 256, 0, stream>>>(x, lnf_g, lnf_b, h);
    gemm_kernel<true, false, false><<<dim3(V_ / 64, M / 128), 256, 0, stream>>>(
        h, lm_w, lm_b, nullptr, out, M, V_, C_);
}